// Round 4
// baseline (59.092 us; speedup 1.0000x reference)
//
#include <hip/hip_runtime.h>
#include <hip/hip_bf16.h>

// ---- problem constants ----
#define BATCH 16
#define CIN   12
#define HIMG  512
#define WIMG  512
#define OCH   768
#define KDIM  256            // 16*16 patch
#define HW    (HIMG*WIMG)    // 262144
#define NPATCH 1024          // 32*32 patches per batch

typedef __attribute__((ext_vector_type(8))) short short8;   // 8 bf16 = 4 VGPRs
typedef __attribute__((ext_vector_type(4))) float f32x4;    // clang vector: ok for nontemporal builtins

// ---------------------------------------------------------------------------
// Kernel 0: convert + PACK weights f32 -> bf16 in MFMA fragment-lane order.
//   packed[u][0..7], u = (ot*8 + kk)*64 + lane
//   holds w[ot*16 + (lane&15)][kk*32 + (lane>>4)*8 + j], j=0..7
// ---------------------------------------------------------------------------
__global__ void wpack_kernel(const float* __restrict__ w, short8* __restrict__ wbp) {
    int u = blockIdx.x * 256 + threadIdx.x;      // 0..24575
    int lane = u & 63;
    int kk   = (u >> 6) & 7;
    int ot   = u >> 9;                           // 0..47
    int o = ot * 16 + (lane & 15);
    int k = kk * 32 + (lane >> 4) * 8;
    const float* src = w + (size_t)o * KDIM + k;
    f32x4 v0 = *reinterpret_cast<const f32x4*>(src);
    f32x4 v1 = *reinterpret_cast<const f32x4*>(src + 4);
    union { short8 s; __hip_bfloat16 h[8]; } t;
    t.h[0] = __float2bfloat16(v0.x);
    t.h[1] = __float2bfloat16(v0.y);
    t.h[2] = __float2bfloat16(v0.z);
    t.h[3] = __float2bfloat16(v0.w);
    t.h[4] = __float2bfloat16(v1.x);
    t.h[5] = __float2bfloat16(v1.y);
    t.h[6] = __float2bfloat16(v1.z);
    t.h[7] = __float2bfloat16(v1.w);
    wbp[u] = t.s;
}

// ---------------------------------------------------------------------------
// Kernel 1 (fused, pipelined): channel-mean + patch-embedding GEMM.
// One block = one (batch b, stripe is): 16 rows x 512 cols, all 768 o-chans.
// 512 threads = 8 waves; wave wv owns o-range [wv*96, wv*96+96) x 32 patches
// = 6x2 fragments.  K=256 split into 4 chunks of 64 (== 4 image rows each):
//   chunk pipeline: issue nt-loads(ch+1) -> reduce(ch) -> LDS -> barrier ->
//   24 MFMA(ch).  Loads stay in flight across barriers (T4); MFMA + L2
//   weight reads hide under the HBM stream.
// ---------------------------------------------------------------------------
#define LDB 264   // 256 + 8 pad

__global__ __launch_bounds__(512) void fused_kernel(
        const short8* __restrict__ wbp,   // packed weights (L2-resident)
        const float*  __restrict__ x,     // [B][C][H][W]
        const float*  __restrict__ bias,
        float* __restrict__ out) {        // [B][O][32][32]
    __shared__ short Bl[32][LDB];

    const int tid = threadIdx.x;
    const int b  = blockIdx.x >> 5;
    const int is = blockIdx.x & 31;       // stripe index

    // staging geometry: thread owns one float4 quad per chunk
    const int col = (tid & 127) * 4;      // 0..508
    const int r0  = tid >> 7;             // 0..3
    const int j   = col >> 4;             // patch within stripe
    const int s0  = col & 15;
    const float* xb = x + (size_t)b * CIN * HW + (size_t)(is * 16) * WIMG + col;
    const float inv = 1.0f / 12.0f;

    // MFMA geometry
    const int lane = tid & 63;
    const int wv   = tid >> 6;            // 0..7
    const int lrow = lane & 15;
    const int lg   = lane >> 4;
    const short8* wp = wbp + (size_t)(wv * 6) * 8 * 64 + lane;

    f32x4 acc[6][2] = {};
    f32x4 bufA[CIN], bufB[CIN];

#define ISSUE(buf, ch)                                                         \
    {                                                                          \
        const float* p_ = xb + (size_t)((ch) * 4 + r0) * WIMG;                 \
        _Pragma("unroll")                                                      \
        for (int c = 0; c < CIN; ++c)                                          \
            buf[c] = __builtin_nontemporal_load(                               \
                reinterpret_cast<const f32x4*>(p_ + (size_t)c * HW));          \
    }

#define REDUCE_STORE(buf, ch)                                                  \
    {                                                                          \
        float sx = 0.f, sy = 0.f, sz = 0.f, sw = 0.f;                          \
        _Pragma("unroll")                                                      \
        for (int c = 0; c < CIN; ++c) {                                        \
            sx += buf[c].x; sy += buf[c].y; sz += buf[c].z; sw += buf[c].w;    \
        }                                                                      \
        union { ushort4 u4; __hip_bfloat16 h[4]; } o_;                         \
        o_.h[0] = __float2bfloat16(sx * inv);                                  \
        o_.h[1] = __float2bfloat16(sy * inv);                                  \
        o_.h[2] = __float2bfloat16(sz * inv);                                  \
        o_.h[3] = __float2bfloat16(sw * inv);                                  \
        *reinterpret_cast<ushort4*>(&Bl[j][((ch) * 4 + r0) * 16 + s0]) = o_.u4;\
    }

#define MFMA_CHUNK(ch)                                                         \
    {                                                                          \
        _Pragma("unroll")                                                      \
        for (int k2 = 0; k2 < 2; ++k2) {                                       \
            const int kk = (ch) * 2 + k2;                                      \
            short8 af[6], bf[2];                                               \
            _Pragma("unroll")                                                  \
            for (int fo = 0; fo < 6; ++fo)                                     \
                af[fo] = wp[(size_t)(fo * 8 + kk) * 64];                       \
            _Pragma("unroll")                                                  \
            for (int fm = 0; fm < 2; ++fm)                                     \
                bf[fm] = *reinterpret_cast<const short8*>(                     \
                    &Bl[fm * 16 + lrow][kk * 32 + lg * 8]);                    \
            _Pragma("unroll")                                                  \
            for (int fo = 0; fo < 6; ++fo)                                     \
                _Pragma("unroll")                                              \
                for (int fm = 0; fm < 2; ++fm)                                 \
                    acc[fo][fm] = __builtin_amdgcn_mfma_f32_16x16x32_bf16(     \
                        af[fo], bf[fm], acc[fo][fm], 0, 0, 0);                 \
        }                                                                      \
    }

    // ---- depth-2 software pipeline over 4 chunks ----
    ISSUE(bufA, 0);
    ISSUE(bufB, 1);
    REDUCE_STORE(bufA, 0);
    __syncthreads();
    ISSUE(bufA, 2);
    MFMA_CHUNK(0);
    REDUCE_STORE(bufB, 1);
    __syncthreads();
    ISSUE(bufB, 3);
    MFMA_CHUNK(1);
    REDUCE_STORE(bufA, 2);
    __syncthreads();
    MFMA_CHUNK(2);
    REDUCE_STORE(bufB, 3);
    __syncthreads();
    MFMA_CHUNK(3);

    // ---- epilogue: D row = o ((lane>>4)*4 + reg), col = m (lane&15) ----
    const int p0 = is * 32;
    float* ob = out + (size_t)b * OCH * NPATCH + p0;
    #pragma unroll
    for (int fo = 0; fo < 6; ++fo) {
        const int obase = wv * 96 + fo * 16 + lg * 4;
        #pragma unroll
        for (int r = 0; r < 4; ++r) {
            const int o = obase + r;
            const float bv = bias[o];
            float* orow = ob + (size_t)o * NPATCH;
            #pragma unroll
            for (int fm = 0; fm < 2; ++fm)
                orow[fm * 16 + lrow] = acc[fo][fm][r] + bv;
        }
    }
}

// ---------------------------------------------------------------------------
extern "C" void kernel_launch(void* const* d_in, const int* in_sizes, int n_in,
                              void* d_out, int out_size, void* d_ws, size_t ws_size,
                              hipStream_t stream) {
    const float* x    = (const float*)d_in[0];
    const float* w    = (const float*)d_in[1];
    const float* bias = (const float*)d_in[2];
    float* out = (float*)d_out;

    short8* wbp = (short8*)d_ws;   // 393 KiB packed bf16 weights

    wpack_kernel<<<96, 256, 0, stream>>>(w, wbp);
    fused_kernel<<<BATCH * 32, 512, 0, stream>>>(wbp, x, bias, out);
}